// Round 2
// baseline (5301.859 us; speedup 1.0000x reference)
//
#include <hip/hip_runtime.h>

// ---------------------------------------------------------------------------
// LightGCN on MI355X, v2:
//   - bucketed partition (coalesced run writes) instead of exact random scatter
//   - SpMM: block-per-bucket, LDS f32 atomic accumulators (ds_add_f32)
//   - layer 1 fused with x0 init (reads embedding tables directly)
// Node layout: x = [user_weight; item_weight], N = NU + NI, d = 64.
// ---------------------------------------------------------------------------

#define MAXBUK 640   // >= ceil(150000/256) = 586
#define CHUNK 4096   // edges per partition block

__device__ __forceinline__ int wave_incl_scan(int v) {
  int lane = threadIdx.x & 63;
#pragma unroll
  for (int off = 1; off < 64; off <<= 1) {
    int t = __shfl_up(v, off, 64);
    if (lane >= off) v += t;
  }
  return v;
}

__global__ void hist_k(const int4* __restrict__ col4, int E4, const int* __restrict__ col,
                       int E, int* __restrict__ deg) {
  int i = blockIdx.x * blockDim.x + threadIdx.x;
  int stride = gridDim.x * blockDim.x;
  for (int j = i; j < E4; j += stride) {
    int4 c = col4[j];
    atomicAdd(&deg[c.x], 1);
    atomicAdd(&deg[c.y], 1);
    atomicAdd(&deg[c.z], 1);
    atomicAdd(&deg[c.w], 1);
  }
  // tail
  for (int j = E4 * 4 + i; j < E; j += stride) atomicAdd(&deg[col[j]], 1);
}

__global__ void dis_k(const int* __restrict__ deg, float* __restrict__ dis, int N) {
  int i = blockIdx.x * blockDim.x + threadIdx.x;
  if (i < N) {
    int d = deg[i];
    dis[i] = d > 0 ? 1.0f / sqrtf((float)d) : 0.0f;
  }
}

// --- 3-phase exclusive scan of deg[0..N) into offs[0..N], offs[N] = E -------

__global__ void partial_sum_k(const int* __restrict__ deg, int N, int* __restrict__ partials) {
  int base = blockIdx.x * 1024;
  int tid = threadIdx.x;  // 256
  int s = 0;
#pragma unroll
  for (int j = 0; j < 4; ++j) {
    int i = base + j * 256 + tid;
    if (i < N) s += deg[i];
  }
#pragma unroll
  for (int off = 1; off < 64; off <<= 1) s += __shfl_xor(s, off, 64);
  __shared__ int ws_[4];
  int wid = tid >> 6;
  if ((tid & 63) == 0) ws_[wid] = s;
  __syncthreads();
  if (tid == 0) partials[blockIdx.x] = ws_[0] + ws_[1] + ws_[2] + ws_[3];
}

__global__ void scan_partials_k(int* __restrict__ partials, int NB) {
  int tid = threadIdx.x;  // 1024, requires NB <= 1024
  int v = (tid < NB) ? partials[tid] : 0;
  int incl = wave_incl_scan(v);
  __shared__ int wsum[16];
  int wid = tid >> 6, lane = tid & 63;
  if (lane == 63) wsum[wid] = incl;
  __syncthreads();
  if (tid == 0) {
    int run = 0;
#pragma unroll
    for (int j = 0; j < 16; ++j) { int t = wsum[j]; wsum[j] = run; run += t; }
  }
  __syncthreads();
  if (tid < NB) partials[tid] = incl - v + wsum[wid];
}

__global__ void scan_apply_k(const int* __restrict__ deg, const int* __restrict__ partials,
                             int* __restrict__ offs, int N, int E) {
  int i = blockIdx.x * 1024 + threadIdx.x;
  int v = (i < N) ? deg[i] : 0;
  int incl = wave_incl_scan(v);
  __shared__ int wsum[16];
  int wid = threadIdx.x >> 6, lane = threadIdx.x & 63;
  if (lane == 63) wsum[wid] = incl;
  __syncthreads();
  if (threadIdx.x == 0) {
    int run = 0;
#pragma unroll
    for (int j = 0; j < 16; ++j) { int t = wsum[j]; wsum[j] = run; run += t; }
  }
  __syncthreads();
  if (i < N) offs[i] = incl - v + wsum[wid] + partials[blockIdx.x];
  if (i == 0 && blockIdx.x == 0) offs[N] = E;
}

__global__ void gcur_init_k(const int* __restrict__ offs, int* __restrict__ gcursor, int nbuk) {
  int b = blockIdx.x * 256 + threadIdx.x;
  if (b < nbuk) gcursor[b] = offs[b << 8];
}

// --- bucketed partition: edges grouped into 256-node dst buckets ------------
// record = { src | (dst&255)<<18 , float_bits(norm) }

__global__ __launch_bounds__(256) void partition_k(
    const int* __restrict__ row, const int* __restrict__ col, int E,
    const float* __restrict__ dis, int* __restrict__ gcursor,
    int2* __restrict__ eout, int nbuk) {
  __shared__ int cnt[MAXBUK];
  __shared__ int start[MAXBUK];
  __shared__ int ghead[MAXBUK];
  __shared__ int2 ebuf[CHUNK];
  __shared__ int gofs[CHUNK];
  __shared__ int wsum[4];

  const int tid = threadIdx.x;
  const int base = blockIdx.x * CHUNK;
  const int m = min(CHUNK, E - base);

  for (int b = tid; b < nbuk; b += 256) cnt[b] = 0;
  __syncthreads();

  int2 rec[16];
  int bb[16];
#pragma unroll
  for (int k = 0; k < 16; ++k) {
    int idx = k * 256 + tid;
    bb[k] = -1;
    if (idx < m) {
      int i = base + idx;
      int c = col[i];
      int r = row[i];
      int b = c >> 8;
      float w = dis[r] * dis[c];
      rec[k] = make_int2(r | ((c & 255) << 18), __float_as_int(w));
      bb[k] = b;
      atomicAdd(&cnt[b], 1);
    }
  }
  __syncthreads();

  // exclusive scan of cnt[0..nbuk) into start[]
  const int b0 = tid * 3;  // 3 buckets per thread covers 768 >= nbuk
  int lc0 = (b0 + 0 < nbuk) ? cnt[b0 + 0] : 0;
  int lc1 = (b0 + 1 < nbuk) ? cnt[b0 + 1] : 0;
  int lc2 = (b0 + 2 < nbuk) ? cnt[b0 + 2] : 0;
  int s = lc0 + lc1 + lc2;
  int incl = wave_incl_scan(s);
  int wid = tid >> 6, lane = tid & 63;
  if (lane == 63) wsum[wid] = incl;
  __syncthreads();
  int wb = 0;
#pragma unroll
  for (int j = 0; j < 4; ++j)
    if (j < wid) wb += wsum[j];
  int run = incl - s + wb;
  if (b0 + 0 < nbuk) { start[b0 + 0] = run; run += lc0; }
  if (b0 + 1 < nbuk) { start[b0 + 1] = run; run += lc1; }
  if (b0 + 2 < nbuk) { start[b0 + 2] = run; run += lc2; }
  __syncthreads();

  // reserve global runs
  for (int b = tid; b < nbuk; b += 256) {
    int cb = cnt[b];
    if (cb > 0) {
      int g = atomicAdd(&gcursor[b], cb);
      ghead[b] = g - start[b];
    }
  }
  __syncthreads();

  // place into ordered LDS buffer (start[] doubles as running cursor)
#pragma unroll
  for (int k = 0; k < 16; ++k) {
    if (bb[k] >= 0) {
      int slot = atomicAdd(&start[bb[k]], 1);
      ebuf[slot] = rec[k];
      gofs[slot] = ghead[bb[k]];
    }
  }
  __syncthreads();

  // coalesced-run writeout: consecutive slots in a bucket -> consecutive global
  for (int s2 = tid; s2 < m; s2 += 256) eout[gofs[s2] + s2] = ebuf[s2];
}

// --- SpMM: one block per 256-node bucket, LDS f32 atomic accumulators -------

template <int LAYER>
__global__ __launch_bounds__(512) void spmm_b(
    const int* __restrict__ offs, const int2* __restrict__ edges,
    const float* __restrict__ uw, const float* __restrict__ iw,
    const float* __restrict__ xin, float* __restrict__ xout,
    float* __restrict__ dout, int N, int NU, int nbuk, int rot) {
  __shared__ float acc[256 * 64];
  const int tid = threadIdx.x;
  const int lane = tid & 63;
  const int wv = tid >> 6;

  int b = blockIdx.x + rot;
  if (b >= nbuk) b -= nbuk;
  const int node0 = b << 8;
  const int nn = min(256, N - node0);

  for (int j = tid; j < 256 * 64; j += 512) acc[j] = 0.0f;
  __syncthreads();

  int e0 = __builtin_amdgcn_readfirstlane(offs[node0]);
  int e1 = __builtin_amdgcn_readfirstlane(offs[node0 + nn]);

  auto body = [&](int ei) {
    int2 rc = edges[ei];
    int pk = rc.x;
    int src = pk & 0x3FFFF;
    int dr = ((unsigned)pk >> 18) & 255;
    float w = __int_as_float(rc.y);
    const float* xp;
    if (LAYER == 1)
      xp = (src < NU) ? (uw + src * 64) : (iw + (src - NU) * 64);
    else
      xp = xin + src * 64;
    float xv = xp[lane];
    atomicAdd(&acc[dr * 64 + lane], w * xv);
  };

  for (int e = e0 + (wv << 2); e < e1; e += 32) {
    if (e + 4 <= e1) {
      int2 r0 = edges[e + 0];
      int2 r1 = edges[e + 1];
      int2 r2 = edges[e + 2];
      int2 r3 = edges[e + 3];
      int s0 = r0.x & 0x3FFFF, d0 = ((unsigned)r0.x >> 18) & 255;
      int s1 = r1.x & 0x3FFFF, d1 = ((unsigned)r1.x >> 18) & 255;
      int s2 = r2.x & 0x3FFFF, d2 = ((unsigned)r2.x >> 18) & 255;
      int s3 = r3.x & 0x3FFFF, d3 = ((unsigned)r3.x >> 18) & 255;
      const float *p0, *p1, *p2, *p3;
      if (LAYER == 1) {
        p0 = (s0 < NU) ? (uw + s0 * 64) : (iw + (s0 - NU) * 64);
        p1 = (s1 < NU) ? (uw + s1 * 64) : (iw + (s1 - NU) * 64);
        p2 = (s2 < NU) ? (uw + s2 * 64) : (iw + (s2 - NU) * 64);
        p3 = (s3 < NU) ? (uw + s3 * 64) : (iw + (s3 - NU) * 64);
      } else {
        p0 = xin + s0 * 64;
        p1 = xin + s1 * 64;
        p2 = xin + s2 * 64;
        p3 = xin + s3 * 64;
      }
      float x0 = p0[lane], x1 = p1[lane], x2 = p2[lane], x3 = p3[lane];
      atomicAdd(&acc[d0 * 64 + lane], __int_as_float(r0.y) * x0);
      atomicAdd(&acc[d1 * 64 + lane], __int_as_float(r1.y) * x1);
      atomicAdd(&acc[d2 * 64 + lane], __int_as_float(r2.y) * x2);
      atomicAdd(&acc[d3 * 64 + lane], __int_as_float(r3.y) * x3);
    } else {
      for (int t = 0; t < e1 - e; ++t) body(e + t);
    }
  }
  __syncthreads();

  for (int j = wv; j < nn; j += 8) {
    int n = node0 + j;
    int o = n * 64 + lane;
    float a = acc[j * 64 + lane];
    if (LAYER == 1) {
      float x0 = (n < NU) ? uw[o] : iw[o - NU * 64];
      xout[o] = a;
      dout[o] = x0 + a;
    } else if (LAYER == 2) {
      xout[o] = a;
      dout[o] += a;
    } else {
      dout[o] = (dout[o] + a) * 0.25f;
    }
  }
}

extern "C" void kernel_launch(void* const* d_in, const int* in_sizes, int n_in,
                              void* d_out, int out_size, void* d_ws, size_t ws_size,
                              hipStream_t stream) {
  const int* edge_index = (const int*)d_in[0];
  const float* uw = (const float*)d_in[1];
  const float* iw = (const float*)d_in[2];
  const int E = in_sizes[0] / 2;
  const int NU = in_sizes[1] / 64;
  const int NI = in_sizes[2] / 64;
  const int N = NU + NI;
  const int NB = (N + 1023) / 1024;
  const int nbuk = (N + 255) >> 8;
  const int rot = NU >> 8;  // process item buckets (2x degree) first

  const int* row = edge_index;      // edge_index[0, :]
  const int* col = edge_index + E;  // edge_index[1, :]

  char* w = (char*)d_ws;
  auto carve = [&](size_t bytes) {
    char* p = w;
    w += (bytes + 255) & ~(size_t)255;
    return (void*)p;
  };
  int* deg = (int*)carve((size_t)N * sizeof(int));
  int* offs = (int*)carve((size_t)(N + 1) * sizeof(int));
  int* partials = (int*)carve((size_t)NB * sizeof(int));
  float* dis = (float*)carve((size_t)N * sizeof(float));
  int* gcursor = (int*)carve((size_t)MAXBUK * sizeof(int));
  int2* edges = (int2*)carve((size_t)E * sizeof(int2));
  float* xa = (float*)carve((size_t)N * 64 * sizeof(float));
  float* xb = (float*)carve((size_t)N * 64 * sizeof(float));

  float* out = (float*)d_out;

  hipMemsetAsync(deg, 0, (size_t)N * sizeof(int), stream);
  hist_k<<<2048, 256, 0, stream>>>((const int4*)col, E / 4, col, E, deg);
  dis_k<<<(N + 255) / 256, 256, 0, stream>>>(deg, dis, N);
  partial_sum_k<<<NB, 256, 0, stream>>>(deg, N, partials);
  scan_partials_k<<<1, 1024, 0, stream>>>(partials, NB);
  scan_apply_k<<<NB, 1024, 0, stream>>>(deg, partials, offs, N, E);
  gcur_init_k<<<(nbuk + 255) / 256, 256, 0, stream>>>(offs, gcursor, nbuk);
  partition_k<<<(E + CHUNK - 1) / CHUNK, 256, 0, stream>>>(row, col, E, dis, gcursor, edges, nbuk);

  // layer 1: x0 from tables, writes xb and dout = x0 + l1
  spmm_b<1><<<nbuk, 512, 0, stream>>>(offs, edges, uw, iw, nullptr, xb, out, N, NU, nbuk, rot);
  // layer 2: xb -> xa, dout += l2
  spmm_b<2><<<nbuk, 512, 0, stream>>>(offs, edges, uw, iw, xb, xa, out, N, NU, nbuk, rot);
  // layer 3: xa -> (none), dout = (dout + l3) * 0.25
  spmm_b<3><<<nbuk, 512, 0, stream>>>(offs, edges, uw, iw, xa, xb, out, N, NU, nbuk, rot);
}

// Round 12
// 710.404 us; speedup vs baseline: 7.4632x; 7.4632x over previous
//
#include <hip/hip_runtime.h>

// ---------------------------------------------------------------------------
// LightGCN on MI355X, v3 (resubmit x9 — R3..R11 benches never ran, GPU timeout):
//   - z-form: iterate kept pre-scaled (z = dis .* x)  =>  edge = 4B src index
//   - exact CSR built coalesced: bucket partition + per-bucket LDS counting sort
//   - SpMM: wave-per-node, lane-parallel edge load + readlane broadcast,
//     8 independent gathers in flight, dummy zero-row N pads tails
// ---------------------------------------------------------------------------

#define MAXBUK 640   // >= ceil(150016/256) = 587
#define CHUNK 4096   // edges per partition block
#define MAXBE 12288  // max edges per 256-node bucket (avg item bucket ~10.2k)

__device__ __forceinline__ int wave_incl_scan(int v) {
  int lane = threadIdx.x & 63;
#pragma unroll
  for (int off = 1; off < 64; off <<= 1) {
    int t = __shfl_up(v, off, 64);
    if (lane >= off) v += t;
  }
  return v;
}

__global__ void hist_k(const int4* __restrict__ col4, int E4, const int* __restrict__ col,
                       int E, int* __restrict__ deg) {
  int i = blockIdx.x * blockDim.x + threadIdx.x;
  int stride = gridDim.x * blockDim.x;
  for (int j = i; j < E4; j += stride) {
    int4 c = col4[j];
    atomicAdd(&deg[c.x], 1);
    atomicAdd(&deg[c.y], 1);
    atomicAdd(&deg[c.z], 1);
    atomicAdd(&deg[c.w], 1);
  }
  for (int j = E4 * 4 + i; j < E; j += stride) atomicAdd(&deg[col[j]], 1);
}

__global__ void dis_k(const int* __restrict__ deg, float* __restrict__ dis,
                      float* __restrict__ dis2, int N) {
  int i = blockIdx.x * blockDim.x + threadIdx.x;
  if (i < N) {
    int d = deg[i];
    float v = d > 0 ? 1.0f / sqrtf((float)d) : 0.0f;
    dis[i] = v;
    dis2[i] = v * v;
  }
}

// --- 3-phase exclusive scan of deg[0..N) into offs[0..N], offs[N] = E -------

__global__ void partial_sum_k(const int* __restrict__ deg, int N, int* __restrict__ partials) {
  int base = blockIdx.x * 1024;
  int tid = threadIdx.x;  // 256
  int s = 0;
#pragma unroll
  for (int j = 0; j < 4; ++j) {
    int i = base + j * 256 + tid;
    if (i < N) s += deg[i];
  }
#pragma unroll
  for (int off = 1; off < 64; off <<= 1) s += __shfl_xor(s, off, 64);
  __shared__ int ws_[4];
  int wid = tid >> 6;
  if ((tid & 63) == 0) ws_[wid] = s;
  __syncthreads();
  if (tid == 0) partials[blockIdx.x] = ws_[0] + ws_[1] + ws_[2] + ws_[3];
}

__global__ void scan_partials_k(int* __restrict__ partials, int NB) {
  int tid = threadIdx.x;  // 1024, requires NB <= 1024
  int v = (tid < NB) ? partials[tid] : 0;
  int incl = wave_incl_scan(v);
  __shared__ int wsum[16];
  int wid = tid >> 6, lane = tid & 63;
  if (lane == 63) wsum[wid] = incl;
  __syncthreads();
  if (tid == 0) {
    int run = 0;
#pragma unroll
    for (int j = 0; j < 16; ++j) { int t = wsum[j]; wsum[j] = run; run += t; }
  }
  __syncthreads();
  if (tid < NB) partials[tid] = incl - v + wsum[wid];
}

__global__ void scan_apply_k(const int* __restrict__ deg, const int* __restrict__ partials,
                             int* __restrict__ offs, int N, int E) {
  int i = blockIdx.x * 1024 + threadIdx.x;
  int v = (i < N) ? deg[i] : 0;
  int incl = wave_incl_scan(v);
  __shared__ int wsum[16];
  int wid = threadIdx.x >> 6, lane = threadIdx.x & 63;
  if (lane == 63) wsum[wid] = incl;
  __syncthreads();
  if (threadIdx.x == 0) {
    int run = 0;
#pragma unroll
    for (int j = 0; j < 16; ++j) { int t = wsum[j]; wsum[j] = run; run += t; }
  }
  __syncthreads();
  if (i < N) offs[i] = incl - v + wsum[wid] + partials[blockIdx.x];
  if (i == 0 && blockIdx.x == 0) offs[N] = E;
}

__global__ void gcur_init_k(const int* __restrict__ offs, int* __restrict__ gcursor, int nbuk) {
  int b = blockIdx.x * 256 + threadIdx.x;
  if (b < nbuk) gcursor[b] = offs[b << 8];
}

// --- pass A: bucket partition, record = src | dst_rel<<18 (4B), coalesced ---

__global__ __launch_bounds__(256) void part_k(
    const int* __restrict__ row, const int* __restrict__ col, int E,
    int* __restrict__ gcursor, int* __restrict__ ebk, int nbuk) {
  __shared__ int cnt[MAXBUK];
  __shared__ int start[MAXBUK];
  __shared__ int ghead[MAXBUK];
  __shared__ int ebuf[CHUNK];
  __shared__ int gofs[CHUNK];
  __shared__ int wsum[4];

  const int tid = threadIdx.x;
  const int base = blockIdx.x * CHUNK;
  const int m = min(CHUNK, E - base);

  for (int b = tid; b < nbuk; b += 256) cnt[b] = 0;
  __syncthreads();

  int rec[16];
  int bb[16];
#pragma unroll
  for (int k = 0; k < 16; ++k) {
    int idx = k * 256 + tid;
    bb[k] = -1;
    if (idx < m) {
      int i = base + idx;
      int c = col[i];
      int r = row[i];
      rec[k] = r | ((c & 255) << 18);
      bb[k] = c >> 8;
      atomicAdd(&cnt[c >> 8], 1);
    }
  }
  __syncthreads();

  // exclusive scan of cnt[0..nbuk) into start[]
  const int b0 = tid * 3;  // 3 buckets/thread covers 768 >= nbuk
  int lc0 = (b0 + 0 < nbuk) ? cnt[b0 + 0] : 0;
  int lc1 = (b0 + 1 < nbuk) ? cnt[b0 + 1] : 0;
  int lc2 = (b0 + 2 < nbuk) ? cnt[b0 + 2] : 0;
  int s = lc0 + lc1 + lc2;
  int incl = wave_incl_scan(s);
  int wid = tid >> 6, lane = tid & 63;
  if (lane == 63) wsum[wid] = incl;
  __syncthreads();
  int wb = 0;
#pragma unroll
  for (int j = 0; j < 4; ++j)
    if (j < wid) wb += wsum[j];
  int run = incl - s + wb;
  if (b0 + 0 < nbuk) { start[b0 + 0] = run; run += lc0; }
  if (b0 + 1 < nbuk) { start[b0 + 1] = run; run += lc1; }
  if (b0 + 2 < nbuk) { start[b0 + 2] = run; run += lc2; }
  __syncthreads();

  // reserve global runs
  for (int b = tid; b < nbuk; b += 256) {
    int cb = cnt[b];
    if (cb > 0) {
      int g = atomicAdd(&gcursor[b], cb);
      ghead[b] = g - start[b];
    }
  }
  __syncthreads();

  // place into ordered LDS buffer (start[] doubles as running cursor)
#pragma unroll
  for (int k = 0; k < 16; ++k) {
    if (bb[k] >= 0) {
      int slot = atomicAdd(&start[bb[k]], 1);
      ebuf[slot] = rec[k];
      gofs[slot] = ghead[bb[k]];
    }
  }
  __syncthreads();

  for (int s2 = tid; s2 < m; s2 += 256) ebk[gofs[s2] + s2] = ebuf[s2];
}

// --- pass B: per-bucket LDS counting sort -> exact CSR srcs (4B) ------------

__global__ __launch_bounds__(256) void bsort_k(
    const int* __restrict__ offs, const int* __restrict__ ebk,
    int* __restrict__ srcs, int N, int nbuk) {
  __shared__ int cnt[256];
  __shared__ int wsum[4];
  __shared__ int obuf[MAXBE];
  const int tid = threadIdx.x;
  const int node0 = blockIdx.x << 8;
  const int nn = min(256, N - node0);
  const int g0 = offs[node0];
  const int g1 = offs[node0 + nn];
  const int m = g1 - g0;

  cnt[tid] = 0;
  __syncthreads();
  for (int i = tid; i < m; i += 256) atomicAdd(&cnt[(ebk[g0 + i] >> 18) & 255], 1);
  __syncthreads();

  int v = cnt[tid];
  int incl = wave_incl_scan(v);
  int wid = tid >> 6, lane = tid & 63;
  if (lane == 63) wsum[wid] = incl;
  __syncthreads();
  int wb = 0;
#pragma unroll
  for (int j = 0; j < 4; ++j)
    if (j < wid) wb += wsum[j];
  int excl = incl - v + wb;
  __syncthreads();
  cnt[tid] = excl;
  __syncthreads();

  for (int i = tid; i < m; i += 256) {
    int r = ebk[g0 + i];
    int slot = atomicAdd(&cnt[(r >> 18) & 255], 1);
    if (slot < MAXBE) obuf[slot] = r & 0x3FFFF;
  }
  __syncthreads();
  for (int i = tid; i < m; i += 256) srcs[g0 + i] = obuf[i];
}

// --- z0 = dis .* x0 ; zero dummy row N in both z buffers --------------------

__global__ void initz_k(const float4* __restrict__ uw4, const float4* __restrict__ iw4,
                        const float* __restrict__ dis, float4* __restrict__ za4,
                        float4* __restrict__ zb4, int N, int NU) {
  int i = blockIdx.x * 256 + threadIdx.x;
  int stride = gridDim.x * 256;
  int tot = (N + 1) * 16;
  for (; i < tot; i += stride) {
    int n = i >> 4;
    if (n < N) {
      float4 v = (n < NU) ? uw4[i] : iw4[i - NU * 16];
      float d = dis[n];
      za4[i] = make_float4(v.x * d, v.y * d, v.z * d, v.w * d);
    } else {
      float4 z = make_float4(0.f, 0.f, 0.f, 0.f);
      za4[i] = z;
      zb4[i] = z;
    }
  }
}

// --- SpMM: wave-per-node, S = sum z[src]; z_out = dis2*S; dout += dis*S -----

template <int LAYER>
__global__ __launch_bounds__(256) void spmm_k(
    const int* __restrict__ offs, const int* __restrict__ srcs,
    const float* __restrict__ zin, float* __restrict__ zout,
    const float* __restrict__ uw, const float* __restrict__ iw,
    const float* __restrict__ dis, const float* __restrict__ dis2,
    float* __restrict__ dout, int N, int NU) {
  int wid = blockIdx.x * 4 + (threadIdx.x >> 6);
  int lane = threadIdx.x & 63;
  if (wid >= N) return;
  int NI = N - NU;
  int n = (wid < NI) ? (NU + wid) : (wid - NI);  // items (2x degree) first
  n = __builtin_amdgcn_readfirstlane(n);
  int e0 = __builtin_amdgcn_readfirstlane(offs[n]);
  int e1 = __builtin_amdgcn_readfirstlane(offs[n + 1]);

  float acc = 0.0f;
  for (int base = e0; base < e1; base += 64) {
    int rem = e1 - base;
    int src = (lane < rem) ? srcs[base + lane] : N;  // lanes past end -> zero row
    int kk = min(rem, 64);
    for (int j = 0; j < kk; j += 8) {
#pragma unroll
      for (int t = 0; t < 8; ++t) {
        int s = __builtin_amdgcn_readlane(src, j + t);
        const float* p = zin + (s << 6);
        acc += p[lane];
      }
    }
  }

  float d1 = dis[n];
  int o = n * 64 + lane;
  float xl = d1 * acc;  // this layer's embedding, true space
  if (LAYER == 1) {
    float x0 = (n < NU) ? uw[o] : iw[o - NU * 64];
    zout[o] = dis2[n] * acc;
    dout[o] = x0 + xl;
  } else if (LAYER == 2) {
    zout[o] = dis2[n] * acc;
    dout[o] += xl;
  } else {
    dout[o] = (dout[o] + xl) * 0.25f;
  }
}

extern "C" void kernel_launch(void* const* d_in, const int* in_sizes, int n_in,
                              void* d_out, int out_size, void* d_ws, size_t ws_size,
                              hipStream_t stream) {
  const int* edge_index = (const int*)d_in[0];
  const float* uw = (const float*)d_in[1];
  const float* iw = (const float*)d_in[2];
  const int E = in_sizes[0] / 2;
  const int NU = in_sizes[1] / 64;
  const int NI = in_sizes[2] / 64;
  const int N = NU + NI;
  const int NB = (N + 1023) / 1024;
  const int nbuk = (N + 255) >> 8;

  const int* row = edge_index;      // edge_index[0, :]
  const int* col = edge_index + E;  // edge_index[1, :]

  char* w = (char*)d_ws;
  auto carve = [&](size_t bytes) {
    char* p = w;
    w += (bytes + 255) & ~(size_t)255;
    return (void*)p;
  };
  int* deg = (int*)carve((size_t)N * sizeof(int));
  int* offs = (int*)carve((size_t)(N + 1) * sizeof(int));
  int* partials = (int*)carve((size_t)NB * sizeof(int));
  float* dis = (float*)carve((size_t)N * sizeof(float));
  float* dis2 = (float*)carve((size_t)N * sizeof(float));
  int* gcursor = (int*)carve((size_t)MAXBUK * sizeof(int));
  int* ebk = (int*)carve((size_t)E * sizeof(int));
  int* srcs = (int*)carve((size_t)E * sizeof(int));
  float* za = (float*)carve((size_t)(N + 1) * 64 * sizeof(float));
  float* zb = (float*)carve((size_t)(N + 1) * 64 * sizeof(float));

  float* out = (float*)d_out;

  hipMemsetAsync(deg, 0, (size_t)N * sizeof(int), stream);
  hist_k<<<2048, 256, 0, stream>>>((const int4*)col, E / 4, col, E, deg);
  dis_k<<<(N + 255) / 256, 256, 0, stream>>>(deg, dis, dis2, N);
  partial_sum_k<<<NB, 256, 0, stream>>>(deg, N, partials);
  scan_partials_k<<<1, 1024, 0, stream>>>(partials, NB);
  scan_apply_k<<<NB, 1024, 0, stream>>>(deg, partials, offs, N, E);
  gcur_init_k<<<(nbuk + 255) / 256, 256, 0, stream>>>(offs, gcursor, nbuk);
  part_k<<<(E + CHUNK - 1) / CHUNK, 256, 0, stream>>>(row, col, E, gcursor, ebk, nbuk);
  bsort_k<<<nbuk, 256, 0, stream>>>(offs, ebk, srcs, N, nbuk);
  initz_k<<<2048, 256, 0, stream>>>((const float4*)uw, (const float4*)iw, dis,
                                    (float4*)za, (float4*)zb, N, NU);

  int sb = (N + 3) / 4;  // 4 waves (nodes) per 256-thread block
  spmm_k<1><<<sb, 256, 0, stream>>>(offs, srcs, za, zb, uw, iw, dis, dis2, out, N, NU);
  spmm_k<2><<<sb, 256, 0, stream>>>(offs, srcs, zb, za, uw, iw, dis, dis2, out, N, NU);
  spmm_k<3><<<sb, 256, 0, stream>>>(offs, srcs, za, zb, uw, iw, dis, dis2, out, N, NU);
}

// Round 13
// 555.000 us; speedup vs baseline: 9.5529x; 1.2800x over previous
//
#include <hip/hip_runtime.h>

// ---------------------------------------------------------------------------
// LightGCN on MI355X, v4:
//   v3 + global-atomic histogram removed (R12: hist_k = 161us, 124MB atomic
//   write-thrash). Bucket-level LDS histogram + single-block scan; per-node
//   degree/offs/dis now emitted by bsort_k's counting sort (free).
// ---------------------------------------------------------------------------

#define MAXBUK 640   // >= ceil(150016/256) = 587
#define CHUNK 4096   // edges per partition block
#define MAXBE 12288  // max edges per 256-node bucket (avg item bucket ~10.2k)

__device__ __forceinline__ int wave_incl_scan(int v) {
  int lane = threadIdx.x & 63;
#pragma unroll
  for (int off = 1; off < 64; off <<= 1) {
    int t = __shfl_up(v, off, 64);
    if (lane >= off) v += t;
  }
  return v;
}

// --- bucket histogram: LDS-aggregated, ~300K global atomics vs 4M ----------

__global__ __launch_bounds__(256) void bhist_k(const int4* __restrict__ col4, int E4,
                                               const int* __restrict__ col, int E,
                                               int* __restrict__ bcnt, int nbuk) {
  __shared__ int lc[MAXBUK];
  for (int b = threadIdx.x; b < nbuk; b += 256) lc[b] = 0;
  __syncthreads();
  int i = blockIdx.x * 256 + threadIdx.x;
  int stride = gridDim.x * 256;
  for (int j = i; j < E4; j += stride) {
    int4 c = col4[j];
    atomicAdd(&lc[c.x >> 8], 1);
    atomicAdd(&lc[c.y >> 8], 1);
    atomicAdd(&lc[c.z >> 8], 1);
    atomicAdd(&lc[c.w >> 8], 1);
  }
  for (int j = E4 * 4 + i; j < E; j += stride) atomicAdd(&lc[col[j] >> 8], 1);
  __syncthreads();
  for (int b = threadIdx.x; b < nbuk; b += 256) {
    int c = lc[b];
    if (c) atomicAdd(&bcnt[b], c);
  }
}

// --- single-block scan of bucket counts -> boffs[0..nbuk], gcursor init -----

__global__ void bscan_k(const int* __restrict__ bcnt, int* __restrict__ boffs,
                        int* __restrict__ gcursor, int nbuk, int E) {
  int tid = threadIdx.x;  // 1024 >= nbuk
  int v = (tid < nbuk) ? bcnt[tid] : 0;
  int incl = wave_incl_scan(v);
  __shared__ int wsum[16];
  int wid = tid >> 6, lane = tid & 63;
  if (lane == 63) wsum[wid] = incl;
  __syncthreads();
  if (tid == 0) {
    int run = 0;
#pragma unroll
    for (int j = 0; j < 16; ++j) { int t = wsum[j]; wsum[j] = run; run += t; }
  }
  __syncthreads();
  int excl = incl - v + wsum[wid];
  if (tid < nbuk) {
    boffs[tid] = excl;
    gcursor[tid] = excl;
  }
  if (tid == 0) boffs[nbuk] = E;
}

// --- pass A: bucket partition, record = src | dst_rel<<18 (4B), coalesced ---

__global__ __launch_bounds__(256) void part_k(
    const int* __restrict__ row, const int* __restrict__ col, int E,
    int* __restrict__ gcursor, int* __restrict__ ebk, int nbuk) {
  __shared__ int cnt[MAXBUK];
  __shared__ int start[MAXBUK];
  __shared__ int ghead[MAXBUK];
  __shared__ int ebuf[CHUNK];
  __shared__ int gofs[CHUNK];
  __shared__ int wsum[4];

  const int tid = threadIdx.x;
  const int base = blockIdx.x * CHUNK;
  const int m = min(CHUNK, E - base);

  for (int b = tid; b < nbuk; b += 256) cnt[b] = 0;
  __syncthreads();

  int rec[16];
  int bb[16];
#pragma unroll
  for (int k = 0; k < 16; ++k) {
    int idx = k * 256 + tid;
    bb[k] = -1;
    if (idx < m) {
      int i = base + idx;
      int c = col[i];
      int r = row[i];
      rec[k] = r | ((c & 255) << 18);
      bb[k] = c >> 8;
      atomicAdd(&cnt[c >> 8], 1);
    }
  }
  __syncthreads();

  // exclusive scan of cnt[0..nbuk) into start[]
  const int b0 = tid * 3;  // 3 buckets/thread covers 768 >= nbuk
  int lc0 = (b0 + 0 < nbuk) ? cnt[b0 + 0] : 0;
  int lc1 = (b0 + 1 < nbuk) ? cnt[b0 + 1] : 0;
  int lc2 = (b0 + 2 < nbuk) ? cnt[b0 + 2] : 0;
  int s = lc0 + lc1 + lc2;
  int incl = wave_incl_scan(s);
  int wid = tid >> 6, lane = tid & 63;
  if (lane == 63) wsum[wid] = incl;
  __syncthreads();
  int wb = 0;
#pragma unroll
  for (int j = 0; j < 4; ++j)
    if (j < wid) wb += wsum[j];
  int run = incl - s + wb;
  if (b0 + 0 < nbuk) { start[b0 + 0] = run; run += lc0; }
  if (b0 + 1 < nbuk) { start[b0 + 1] = run; run += lc1; }
  if (b0 + 2 < nbuk) { start[b0 + 2] = run; run += lc2; }
  __syncthreads();

  // reserve global runs
  for (int b = tid; b < nbuk; b += 256) {
    int cb = cnt[b];
    if (cb > 0) {
      int g = atomicAdd(&gcursor[b], cb);
      ghead[b] = g - start[b];
    }
  }
  __syncthreads();

  // place into ordered LDS buffer (start[] doubles as running cursor)
#pragma unroll
  for (int k = 0; k < 16; ++k) {
    if (bb[k] >= 0) {
      int slot = atomicAdd(&start[bb[k]], 1);
      ebuf[slot] = rec[k];
      gofs[slot] = ghead[bb[k]];
    }
  }
  __syncthreads();

  for (int s2 = tid; s2 < m; s2 += 256) ebk[gofs[s2] + s2] = ebuf[s2];
}

// --- pass B: per-bucket counting sort -> srcs; emits offs/dis/dis2 free -----

__global__ __launch_bounds__(256) void bsort_k(
    const int* __restrict__ boffs, const int* __restrict__ ebk,
    int* __restrict__ srcs, int* __restrict__ offs,
    float* __restrict__ dis, float* __restrict__ dis2, int N, int E) {
  __shared__ int cnt[256];
  __shared__ int wsum[4];
  __shared__ int obuf[MAXBE];
  const int tid = threadIdx.x;
  const int node0 = blockIdx.x << 8;
  const int nn = min(256, N - node0);
  const int g0 = boffs[blockIdx.x];
  const int g1 = boffs[blockIdx.x + 1];
  const int m = g1 - g0;

  cnt[tid] = 0;
  __syncthreads();
  for (int i = tid; i < m; i += 256) atomicAdd(&cnt[(ebk[g0 + i] >> 18) & 255], 1);
  __syncthreads();

  int v = cnt[tid];  // = degree of node0+tid (bucketing is exact by dst)
  int incl = wave_incl_scan(v);
  int wid = tid >> 6, lane = tid & 63;
  if (lane == 63) wsum[wid] = incl;
  __syncthreads();
  int wb = 0;
#pragma unroll
  for (int j = 0; j < 4; ++j)
    if (j < wid) wb += wsum[j];
  int excl = incl - v + wb;

  if (tid < nn) {
    int node = node0 + tid;
    offs[node] = g0 + excl;
    float dv = v > 0 ? 1.0f / sqrtf((float)v) : 0.0f;
    dis[node] = dv;
    dis2[node] = dv * dv;
  }
  if (blockIdx.x == 0 && tid == 0) offs[N] = E;

  __syncthreads();
  cnt[tid] = excl;
  __syncthreads();

  for (int i = tid; i < m; i += 256) {
    int r = ebk[g0 + i];
    int slot = atomicAdd(&cnt[(r >> 18) & 255], 1);
    if (slot < MAXBE) obuf[slot] = r & 0x3FFFF;
  }
  __syncthreads();
  for (int i = tid; i < m; i += 256) srcs[g0 + i] = obuf[i];
}

// --- z0 = dis .* x0 ; zero dummy row N in both z buffers --------------------

__global__ void initz_k(const float4* __restrict__ uw4, const float4* __restrict__ iw4,
                        const float* __restrict__ dis, float4* __restrict__ za4,
                        float4* __restrict__ zb4, int N, int NU) {
  int i = blockIdx.x * 256 + threadIdx.x;
  int stride = gridDim.x * 256;
  int tot = (N + 1) * 16;
  for (; i < tot; i += stride) {
    int n = i >> 4;
    if (n < N) {
      float4 v = (n < NU) ? uw4[i] : iw4[i - NU * 16];
      float d = dis[n];
      za4[i] = make_float4(v.x * d, v.y * d, v.z * d, v.w * d);
    } else {
      float4 z = make_float4(0.f, 0.f, 0.f, 0.f);
      za4[i] = z;
      zb4[i] = z;
    }
  }
}

// --- SpMM: wave-per-node, S = sum z[src]; z_out = dis2*S; dout += dis*S -----

template <int LAYER>
__global__ __launch_bounds__(256) void spmm_k(
    const int* __restrict__ offs, const int* __restrict__ srcs,
    const float* __restrict__ zin, float* __restrict__ zout,
    const float* __restrict__ uw, const float* __restrict__ iw,
    const float* __restrict__ dis, const float* __restrict__ dis2,
    float* __restrict__ dout, int N, int NU) {
  int wid = blockIdx.x * 4 + (threadIdx.x >> 6);
  int lane = threadIdx.x & 63;
  if (wid >= N) return;
  int NI = N - NU;
  int n = (wid < NI) ? (NU + wid) : (wid - NI);  // items (2x degree) first
  n = __builtin_amdgcn_readfirstlane(n);
  int e0 = __builtin_amdgcn_readfirstlane(offs[n]);
  int e1 = __builtin_amdgcn_readfirstlane(offs[n + 1]);

  float acc = 0.0f;
  for (int base = e0; base < e1; base += 64) {
    int rem = e1 - base;
    int src = (lane < rem) ? srcs[base + lane] : N;  // lanes past end -> zero row
    int kk = min(rem, 64);
    for (int j = 0; j < kk; j += 8) {
#pragma unroll
      for (int t = 0; t < 8; ++t) {
        int s = __builtin_amdgcn_readlane(src, j + t);
        const float* p = zin + (s << 6);
        acc += p[lane];
      }
    }
  }

  float d1 = dis[n];
  int o = n * 64 + lane;
  float xl = d1 * acc;  // this layer's embedding, true space
  if (LAYER == 1) {
    float x0 = (n < NU) ? uw[o] : iw[o - NU * 64];
    zout[o] = dis2[n] * acc;
    dout[o] = x0 + xl;
  } else if (LAYER == 2) {
    zout[o] = dis2[n] * acc;
    dout[o] += xl;
  } else {
    dout[o] = (dout[o] + xl) * 0.25f;
  }
}

extern "C" void kernel_launch(void* const* d_in, const int* in_sizes, int n_in,
                              void* d_out, int out_size, void* d_ws, size_t ws_size,
                              hipStream_t stream) {
  const int* edge_index = (const int*)d_in[0];
  const float* uw = (const float*)d_in[1];
  const float* iw = (const float*)d_in[2];
  const int E = in_sizes[0] / 2;
  const int NU = in_sizes[1] / 64;
  const int NI = in_sizes[2] / 64;
  const int N = NU + NI;
  const int nbuk = (N + 255) >> 8;

  const int* row = edge_index;      // edge_index[0, :]
  const int* col = edge_index + E;  // edge_index[1, :]

  char* w = (char*)d_ws;
  auto carve = [&](size_t bytes) {
    char* p = w;
    w += (bytes + 255) & ~(size_t)255;
    return (void*)p;
  };
  int* bcnt = (int*)carve((size_t)MAXBUK * sizeof(int));
  int* boffs = (int*)carve((size_t)(MAXBUK + 1) * sizeof(int));
  int* gcursor = (int*)carve((size_t)MAXBUK * sizeof(int));
  int* offs = (int*)carve((size_t)(N + 1) * sizeof(int));
  float* dis = (float*)carve((size_t)N * sizeof(float));
  float* dis2 = (float*)carve((size_t)N * sizeof(float));
  int* ebk = (int*)carve((size_t)E * sizeof(int));
  int* srcs = (int*)carve((size_t)E * sizeof(int));
  float* za = (float*)carve((size_t)(N + 1) * 64 * sizeof(float));
  float* zb = (float*)carve((size_t)(N + 1) * 64 * sizeof(float));

  float* out = (float*)d_out;

  hipMemsetAsync(bcnt, 0, (size_t)MAXBUK * sizeof(int), stream);
  bhist_k<<<512, 256, 0, stream>>>((const int4*)col, E / 4, col, E, bcnt, nbuk);
  bscan_k<<<1, 1024, 0, stream>>>(bcnt, boffs, gcursor, nbuk, E);
  part_k<<<(E + CHUNK - 1) / CHUNK, 256, 0, stream>>>(row, col, E, gcursor, ebk, nbuk);
  bsort_k<<<nbuk, 256, 0, stream>>>(boffs, ebk, srcs, offs, dis, dis2, N, E);
  initz_k<<<2048, 256, 0, stream>>>((const float4*)uw, (const float4*)iw, dis,
                                    (float4*)za, (float4*)zb, N, NU);

  int sb = (N + 3) / 4;  // 4 waves (nodes) per 256-thread block
  spmm_k<1><<<sb, 256, 0, stream>>>(offs, srcs, za, zb, uw, iw, dis, dis2, out, N, NU);
  spmm_k<2><<<sb, 256, 0, stream>>>(offs, srcs, zb, za, uw, iw, dis, dis2, out, N, NU);
  spmm_k<3><<<sb, 256, 0, stream>>>(offs, srcs, za, zb, uw, iw, dis, dis2, out, N, NU);
}

// Round 15
// 403.497 us; speedup vs baseline: 13.1398x; 1.3755x over previous
//
#include <hip/hip_runtime.h>

// ---------------------------------------------------------------------------
// LightGCN on MI355X, v5b (v5 compile-fix: manual bf16 bit conversion, no
//   hip_bf16.h — this ROCm's __hip_bfloat16 lacks .data):
//   v4 + bf16 z-iterate (R13: spmm gather-bytes-bound at 4.0 TB/s, 436 MB/layer;
//   z rows 256B->128B halves dominant traffic). dout + x0 tables stay fp32.
// ---------------------------------------------------------------------------

#define MAXBUK 640   // >= ceil(150016/256) = 587
#define CHUNK 4096   // edges per partition block
#define MAXBE 12288  // max edges per 256-node bucket (avg item bucket ~10.2k)

__device__ __forceinline__ ushort f2bf(float f) {  // round-to-nearest-even
  union { float f; unsigned int i; } cv;
  cv.f = f;
  unsigned int u = cv.i + 0x7FFFu + ((cv.i >> 16) & 1u);
  return (ushort)(u >> 16);
}

__device__ __forceinline__ float bf2f(ushort u) {
  union { unsigned int i; float f; } cv;
  cv.i = ((unsigned int)u) << 16;
  return cv.f;
}

__device__ __forceinline__ int wave_incl_scan(int v) {
  int lane = threadIdx.x & 63;
#pragma unroll
  for (int off = 1; off < 64; off <<= 1) {
    int t = __shfl_up(v, off, 64);
    if (lane >= off) v += t;
  }
  return v;
}

// --- bucket histogram: LDS-aggregated, ~300K global atomics vs 4M ----------

__global__ __launch_bounds__(256) void bhist_k(const int4* __restrict__ col4, int E4,
                                               const int* __restrict__ col, int E,
                                               int* __restrict__ bcnt, int nbuk) {
  __shared__ int lc[MAXBUK];
  for (int b = threadIdx.x; b < nbuk; b += 256) lc[b] = 0;
  __syncthreads();
  int i = blockIdx.x * 256 + threadIdx.x;
  int stride = gridDim.x * 256;
  for (int j = i; j < E4; j += stride) {
    int4 c = col4[j];
    atomicAdd(&lc[c.x >> 8], 1);
    atomicAdd(&lc[c.y >> 8], 1);
    atomicAdd(&lc[c.z >> 8], 1);
    atomicAdd(&lc[c.w >> 8], 1);
  }
  for (int j = E4 * 4 + i; j < E; j += stride) atomicAdd(&lc[col[j] >> 8], 1);
  __syncthreads();
  for (int b = threadIdx.x; b < nbuk; b += 256) {
    int c = lc[b];
    if (c) atomicAdd(&bcnt[b], c);
  }
}

// --- single-block scan of bucket counts -> boffs[0..nbuk], gcursor init -----

__global__ void bscan_k(const int* __restrict__ bcnt, int* __restrict__ boffs,
                        int* __restrict__ gcursor, int nbuk, int E) {
  int tid = threadIdx.x;  // 1024 >= nbuk
  int v = (tid < nbuk) ? bcnt[tid] : 0;
  int incl = wave_incl_scan(v);
  __shared__ int wsum[16];
  int wid = tid >> 6, lane = tid & 63;
  if (lane == 63) wsum[wid] = incl;
  __syncthreads();
  if (tid == 0) {
    int run = 0;
#pragma unroll
    for (int j = 0; j < 16; ++j) { int t = wsum[j]; wsum[j] = run; run += t; }
  }
  __syncthreads();
  int excl = incl - v + wsum[wid];
  if (tid < nbuk) {
    boffs[tid] = excl;
    gcursor[tid] = excl;
  }
  if (tid == 0) boffs[nbuk] = E;
}

// --- pass A: bucket partition, record = src | dst_rel<<18 (4B), coalesced ---

__global__ __launch_bounds__(256) void part_k(
    const int* __restrict__ row, const int* __restrict__ col, int E,
    int* __restrict__ gcursor, int* __restrict__ ebk, int nbuk) {
  __shared__ int cnt[MAXBUK];
  __shared__ int start[MAXBUK];
  __shared__ int ghead[MAXBUK];
  __shared__ int ebuf[CHUNK];
  __shared__ int gofs[CHUNK];
  __shared__ int wsum[4];

  const int tid = threadIdx.x;
  const int base = blockIdx.x * CHUNK;
  const int m = min(CHUNK, E - base);

  for (int b = tid; b < nbuk; b += 256) cnt[b] = 0;
  __syncthreads();

  int rec[16];
  int bb[16];
#pragma unroll
  for (int k = 0; k < 16; ++k) {
    int idx = k * 256 + tid;
    bb[k] = -1;
    if (idx < m) {
      int i = base + idx;
      int c = col[i];
      int r = row[i];
      rec[k] = r | ((c & 255) << 18);
      bb[k] = c >> 8;
      atomicAdd(&cnt[c >> 8], 1);
    }
  }
  __syncthreads();

  // exclusive scan of cnt[0..nbuk) into start[]
  const int b0 = tid * 3;  // 3 buckets/thread covers 768 >= nbuk
  int lc0 = (b0 + 0 < nbuk) ? cnt[b0 + 0] : 0;
  int lc1 = (b0 + 1 < nbuk) ? cnt[b0 + 1] : 0;
  int lc2 = (b0 + 2 < nbuk) ? cnt[b0 + 2] : 0;
  int s = lc0 + lc1 + lc2;
  int incl = wave_incl_scan(s);
  int wid = tid >> 6, lane = tid & 63;
  if (lane == 63) wsum[wid] = incl;
  __syncthreads();
  int wb = 0;
#pragma unroll
  for (int j = 0; j < 4; ++j)
    if (j < wid) wb += wsum[j];
  int run = incl - s + wb;
  if (b0 + 0 < nbuk) { start[b0 + 0] = run; run += lc0; }
  if (b0 + 1 < nbuk) { start[b0 + 1] = run; run += lc1; }
  if (b0 + 2 < nbuk) { start[b0 + 2] = run; run += lc2; }
  __syncthreads();

  // reserve global runs
  for (int b = tid; b < nbuk; b += 256) {
    int cb = cnt[b];
    if (cb > 0) {
      int g = atomicAdd(&gcursor[b], cb);
      ghead[b] = g - start[b];
    }
  }
  __syncthreads();

  // place into ordered LDS buffer (start[] doubles as running cursor)
#pragma unroll
  for (int k = 0; k < 16; ++k) {
    if (bb[k] >= 0) {
      int slot = atomicAdd(&start[bb[k]], 1);
      ebuf[slot] = rec[k];
      gofs[slot] = ghead[bb[k]];
    }
  }
  __syncthreads();

  for (int s2 = tid; s2 < m; s2 += 256) ebk[gofs[s2] + s2] = ebuf[s2];
}

// --- pass B: per-bucket counting sort -> srcs; emits offs/dis/dis2 free -----

__global__ __launch_bounds__(256) void bsort_k(
    const int* __restrict__ boffs, const int* __restrict__ ebk,
    int* __restrict__ srcs, int* __restrict__ offs,
    float* __restrict__ dis, float* __restrict__ dis2, int N, int E) {
  __shared__ int cnt[256];
  __shared__ int wsum[4];
  __shared__ int obuf[MAXBE];
  const int tid = threadIdx.x;
  const int node0 = blockIdx.x << 8;
  const int nn = min(256, N - node0);
  const int g0 = boffs[blockIdx.x];
  const int g1 = boffs[blockIdx.x + 1];
  const int m = g1 - g0;

  cnt[tid] = 0;
  __syncthreads();
  for (int i = tid; i < m; i += 256) atomicAdd(&cnt[(ebk[g0 + i] >> 18) & 255], 1);
  __syncthreads();

  int v = cnt[tid];  // = degree of node0+tid (bucketing is exact by dst)
  int incl = wave_incl_scan(v);
  int wid = tid >> 6, lane = tid & 63;
  if (lane == 63) wsum[wid] = incl;
  __syncthreads();
  int wb = 0;
#pragma unroll
  for (int j = 0; j < 4; ++j)
    if (j < wid) wb += wsum[j];
  int excl = incl - v + wb;

  if (tid < nn) {
    int node = node0 + tid;
    offs[node] = g0 + excl;
    float dv = v > 0 ? 1.0f / sqrtf((float)v) : 0.0f;
    dis[node] = dv;
    dis2[node] = dv * dv;
  }
  if (blockIdx.x == 0 && tid == 0) offs[N] = E;

  __syncthreads();
  cnt[tid] = excl;
  __syncthreads();

  for (int i = tid; i < m; i += 256) {
    int r = ebk[g0 + i];
    int slot = atomicAdd(&cnt[(r >> 18) & 255], 1);
    if (slot < MAXBE) obuf[slot] = r & 0x3FFFF;
  }
  __syncthreads();
  for (int i = tid; i < m; i += 256) srcs[g0 + i] = obuf[i];
}

// --- z0 = bf16(dis .* x0) ; zero dummy row N in both z buffers --------------
// thread handles 4 elems: reads float4, writes 4 bf16 (8B).

__global__ void initz_k(const float4* __restrict__ uw4, const float4* __restrict__ iw4,
                        const float* __restrict__ dis, ushort* __restrict__ za,
                        ushort* __restrict__ zb, int N, int NU) {
  int i = blockIdx.x * 256 + threadIdx.x;
  int stride = gridDim.x * 256;
  int tot = (N + 1) * 16;
  for (; i < tot; i += stride) {
    int n = i >> 4;
    ushort4 o;
    if (n < N) {
      float4 v = (n < NU) ? uw4[i] : iw4[i - NU * 16];
      float d = dis[n];
      o.x = f2bf(v.x * d);
      o.y = f2bf(v.y * d);
      o.z = f2bf(v.z * d);
      o.w = f2bf(v.w * d);
      *reinterpret_cast<ushort4*>(&za[i * 4]) = o;
    } else {
      o.x = o.y = o.z = o.w = 0;
      *reinterpret_cast<ushort4*>(&za[i * 4]) = o;
      *reinterpret_cast<ushort4*>(&zb[i * 4]) = o;
    }
  }
}

// --- SpMM: wave-per-node, S = sum z[src] (bf16 gather, fp32 accum) ----------

template <int LAYER>
__global__ __launch_bounds__(256) void spmm_k(
    const int* __restrict__ offs, const int* __restrict__ srcs,
    const ushort* __restrict__ zin, ushort* __restrict__ zout,
    const float* __restrict__ uw, const float* __restrict__ iw,
    const float* __restrict__ dis, const float* __restrict__ dis2,
    float* __restrict__ dout, int N, int NU) {
  int wid = blockIdx.x * 4 + (threadIdx.x >> 6);
  int lane = threadIdx.x & 63;
  if (wid >= N) return;
  int NI = N - NU;
  int n = (wid < NI) ? (NU + wid) : (wid - NI);  // items (2x degree) first
  n = __builtin_amdgcn_readfirstlane(n);
  int e0 = __builtin_amdgcn_readfirstlane(offs[n]);
  int e1 = __builtin_amdgcn_readfirstlane(offs[n + 1]);

  float acc = 0.0f;
  for (int base = e0; base < e1; base += 64) {
    int rem = e1 - base;
    int src = (lane < rem) ? srcs[base + lane] : N;  // lanes past end -> zero row
    int kk = min(rem, 64);
    for (int j = 0; j < kk; j += 8) {
      ushort g0_, g1_, g2_, g3_, g4_, g5_, g6_, g7_;
      {
        int s0 = __builtin_amdgcn_readlane(src, j + 0);
        int s1 = __builtin_amdgcn_readlane(src, j + 1);
        int s2 = __builtin_amdgcn_readlane(src, j + 2);
        int s3 = __builtin_amdgcn_readlane(src, j + 3);
        int s4 = __builtin_amdgcn_readlane(src, j + 4);
        int s5 = __builtin_amdgcn_readlane(src, j + 5);
        int s6 = __builtin_amdgcn_readlane(src, j + 6);
        int s7 = __builtin_amdgcn_readlane(src, j + 7);
        g0_ = zin[(s0 << 6) + lane];
        g1_ = zin[(s1 << 6) + lane];
        g2_ = zin[(s2 << 6) + lane];
        g3_ = zin[(s3 << 6) + lane];
        g4_ = zin[(s4 << 6) + lane];
        g5_ = zin[(s5 << 6) + lane];
        g6_ = zin[(s6 << 6) + lane];
        g7_ = zin[(s7 << 6) + lane];
      }
      acc += bf2f(g0_);
      acc += bf2f(g1_);
      acc += bf2f(g2_);
      acc += bf2f(g3_);
      acc += bf2f(g4_);
      acc += bf2f(g5_);
      acc += bf2f(g6_);
      acc += bf2f(g7_);
    }
  }

  float d1 = dis[n];
  int o = n * 64 + lane;
  float xl = d1 * acc;  // this layer's embedding, true space
  if (LAYER == 1) {
    float x0 = (n < NU) ? uw[o] : iw[o - NU * 64];
    zout[o] = f2bf(dis2[n] * acc);
    dout[o] = x0 + xl;
  } else if (LAYER == 2) {
    zout[o] = f2bf(dis2[n] * acc);
    dout[o] += xl;
  } else {
    dout[o] = (dout[o] + xl) * 0.25f;
  }
}

extern "C" void kernel_launch(void* const* d_in, const int* in_sizes, int n_in,
                              void* d_out, int out_size, void* d_ws, size_t ws_size,
                              hipStream_t stream) {
  const int* edge_index = (const int*)d_in[0];
  const float* uw = (const float*)d_in[1];
  const float* iw = (const float*)d_in[2];
  const int E = in_sizes[0] / 2;
  const int NU = in_sizes[1] / 64;
  const int NI = in_sizes[2] / 64;
  const int N = NU + NI;
  const int nbuk = (N + 255) >> 8;

  const int* row = edge_index;      // edge_index[0, :]
  const int* col = edge_index + E;  // edge_index[1, :]

  char* w = (char*)d_ws;
  auto carve = [&](size_t bytes) {
    char* p = w;
    w += (bytes + 255) & ~(size_t)255;
    return (void*)p;
  };
  int* bcnt = (int*)carve((size_t)MAXBUK * sizeof(int));
  int* boffs = (int*)carve((size_t)(MAXBUK + 1) * sizeof(int));
  int* gcursor = (int*)carve((size_t)MAXBUK * sizeof(int));
  int* offs = (int*)carve((size_t)(N + 1) * sizeof(int));
  float* dis = (float*)carve((size_t)N * sizeof(float));
  float* dis2 = (float*)carve((size_t)N * sizeof(float));
  int* ebk = (int*)carve((size_t)E * sizeof(int));
  int* srcs = (int*)carve((size_t)E * sizeof(int));
  ushort* za = (ushort*)carve((size_t)(N + 1) * 64 * sizeof(ushort));
  ushort* zb = (ushort*)carve((size_t)(N + 1) * 64 * sizeof(ushort));

  float* out = (float*)d_out;

  (void)hipMemsetAsync(bcnt, 0, (size_t)MAXBUK * sizeof(int), stream);
  bhist_k<<<512, 256, 0, stream>>>((const int4*)col, E / 4, col, E, bcnt, nbuk);
  bscan_k<<<1, 1024, 0, stream>>>(bcnt, boffs, gcursor, nbuk, E);
  part_k<<<(E + CHUNK - 1) / CHUNK, 256, 0, stream>>>(row, col, E, gcursor, ebk, nbuk);
  bsort_k<<<nbuk, 256, 0, stream>>>(boffs, ebk, srcs, offs, dis, dis2, N, E);
  initz_k<<<2048, 256, 0, stream>>>((const float4*)uw, (const float4*)iw, dis,
                                    za, zb, N, NU);

  int sb = (N + 3) / 4;  // 4 waves (nodes) per 256-thread block
  spmm_k<1><<<sb, 256, 0, stream>>>(offs, srcs, za, zb, uw, iw, dis, dis2, out, N, NU);
  spmm_k<2><<<sb, 256, 0, stream>>>(offs, srcs, zb, za, uw, iw, dis, dis2, out, N, NU);
  spmm_k<3><<<sb, 256, 0, stream>>>(offs, srcs, za, zb, uw, iw, dis, dis2, out, N, NU);
}